// Round 2
// baseline (1634.806 us; speedup 1.0000x reference)
//
#include <hip/hip_runtime.h>

typedef unsigned short ushort_t;
typedef unsigned int uint_t;

typedef __bf16 bf16x8 __attribute__((ext_vector_type(8)));
typedef float f32x4 __attribute__((ext_vector_type(4)));

#define NPTS (1 << 20)

// ---- ws layout (ushort units) ----
#define OFF_FLAG 0        // uint flag at ws[0..1]: 1 = inputs are bf16, 0 = fp32
#define OFF_B0   16
#define OFF_B1   272
#define OFF_B2   528
#define OFF_B3   784
#define OFF_BSIG 1040
#define OFF_BRGB 1041
#define OFF_W0   1056     // K=64 (47 padded), N=256: 32 tiles * 512
#define OFF_W1   17440    // K=256,N=256: 128 tiles * 512
#define OFF_W2   82976
#define OFF_W3   148512
#define OFF_WH   214048   // K=256,N=16 (rgb0,rgb1,rgb2,sig,0...): 8 tiles * 512
#define OFF_PL   218144   // transposed planes [plane][pos(16384)][rank(8)]

__device__ __forceinline__ float bf2f(ushort_t u) {
  union { uint_t i; float f; } c; c.i = ((uint_t)u) << 16; return c.f;
}
__device__ __forceinline__ ushort_t f2bf(float f) {
  union { float f; uint_t i; } c; c.f = f;
  uint_t x = c.i;
  return (ushort_t)((x + 0x7fffu + ((x >> 16) & 1u)) >> 16);
}
// dtype-branched scalar loads
__device__ __forceinline__ float ldf(const void* p, long i, int isbf) {
  return isbf ? bf2f(((const ushort_t*)p)[i]) : ((const float*)p)[i];
}
__device__ __forceinline__ ushort_t ldbf(const void* p, long i, int isbf) {
  return isbf ? ((const ushort_t*)p)[i] : f2bf(((const float*)p)[i]);
}
__device__ __forceinline__ void stf(void* p, long i, int isbf, float v) {
  if (isbf) ((ushort_t*)p)[i] = f2bf(v);
  else      ((float*)p)[i] = v;
}

// XOR-swizzled LDS activation address (row-major 128 x 256 bf16, 16B-group swizzle)
__device__ __forceinline__ int act_addr(int row, int k) {
  return row * 256 + ((((k >> 3) ^ (row & 31)) << 3) | (k & 7));
}

// ------------------------------------------------------------------
// sniff: decide whether inputs are stored as bf16 or fp32.
// Even-index ushorts of an fp32 array are random mantissa halves
// (~15% have exponent field in (100,140)); of a bf16 N(0,1) array they
// are well-formed values (~100%).
// ------------------------------------------------------------------
__global__ void sniff_dtype(const void* __restrict__ f, ushort_t* __restrict__ ws) {
  __shared__ int s_cnt;
  if (threadIdx.x == 0) s_cnt = 0;
  __syncthreads();
  const ushort_t* u = (const ushort_t*)f;
  int c = 0;
  for (int j = 0; j < 4; ++j) {
    ushort_t v = u[(threadIdx.x * 4 + j) * 2];
    int e = (v >> 7) & 0xFF;
    if (e > 100 && e < 140) ++c;
  }
  atomicAdd(&s_cnt, c);
  __syncthreads();
  if (threadIdx.x == 0) ((uint_t*)ws)[0] = (s_cnt >= 160) ? 1u : 0u;
}

__global__ void prep_bias(const void* __restrict__ b0, const void* __restrict__ b1,
                          const void* __restrict__ b2, const void* __restrict__ b3,
                          const void* __restrict__ bsig, const void* __restrict__ brgb,
                          ushort_t* __restrict__ ws) {
  const int isbf = (int)((const uint_t*)ws)[0];
  int i = threadIdx.x;
  ws[OFF_B0 + i] = ldbf(b0, i, isbf);
  ws[OFF_B1 + i] = ldbf(b1, i, isbf);
  ws[OFF_B2 + i] = ldbf(b2, i, isbf);
  ws[OFF_B3 + i] = ldbf(b3, i, isbf);
  if (i == 0) ws[OFF_BSIG] = ldbf(bsig, 0, isbf);
  if (i < 3) ws[OFF_BRGB + i] = ldbf(brgb, i, isbf);
}

// ------------------------------------------------------------------
// prep: swizzle weights into MFMA B-fragment-native layout
// ------------------------------------------------------------------
__global__ void prep_weights(const void* __restrict__ W0,
                             const void* __restrict__ W1,
                             const void* __restrict__ W2,
                             const void* __restrict__ W3,
                             const void* __restrict__ Wsig,
                             const void* __restrict__ Wrgb,
                             ushort_t* __restrict__ ws) {
  const int isbf = (int)((const uint_t*)ws)[0];
  int t = blockIdx.x * 256 + threadIdx.x;   // 424 tiles * 64 lanes = 27136
  int lane = t & 63;
  int tile = t >> 6;
  const void* src = nullptr;
  ushort_t* dst;
  int kt, nt, Ksrc = 256;
  bool head = false;
  if (tile < 32) {            // L0: 47x256 padded to 64x256
    kt = tile >> 4; nt = tile & 15; src = W0; Ksrc = 47;
    dst = ws + OFF_W0 + (size_t)tile * 512;
  } else if (tile < 160) {
    int tl = tile - 32; kt = tl >> 4; nt = tl & 15; src = W1;
    dst = ws + OFF_W1 + (size_t)tl * 512;
  } else if (tile < 288) {
    int tl = tile - 160; kt = tl >> 4; nt = tl & 15; src = W2;
    dst = ws + OFF_W2 + (size_t)tl * 512;
  } else if (tile < 416) {
    int tl = tile - 288; kt = tl >> 4; nt = tl & 15; src = W3;
    dst = ws + OFF_W3 + (size_t)tl * 512;
  } else {                    // head: cols 0..2 = W_rgb, col 3 = W_sig
    int tl = tile - 416; kt = tl; nt = 0; head = true;
    dst = ws + OFF_WH + (size_t)tl * 512;
  }
  int n = nt * 16 + (lane & 15);
  int kb = kt * 32 + (lane >> 4) * 8;
  for (int i = 0; i < 8; ++i) {
    int k = kb + i;
    ushort_t v = 0;
    if (head) {
      if (n < 3) v = ldbf(Wrgb, (long)k * 3 + n, isbf);
      else if (n == 3) v = ldbf(Wsig, k, isbf);
    } else if (k < Ksrc) {
      v = ldbf(src, (long)k * 256 + n, isbf);
    }
    dst[lane * 8 + i] = v;
  }
}

// transpose planes from [rank][pos] to [pos][rank]
__global__ void prep_planes(const void* __restrict__ fxy,
                            const void* __restrict__ fxz,
                            const void* __restrict__ fyz,
                            ushort_t* __restrict__ ws) {
  const int isbf = (int)((const uint_t*)ws)[0];
  int t = blockIdx.x * 256 + threadIdx.x;   // 3*16384 = 49152
  int plane = t >> 14, pos = t & 16383;
  const void* src = (plane == 0) ? fxy : (plane == 1) ? fxz : fyz;
  ushort_t* d = ws + OFF_PL + (size_t)plane * 131072 + (size_t)pos * 8;
  for (int r = 0; r < 8; ++r) d[r] = ldbf(src, (long)r * 16384 + pos, isbf);
}

// ------------------------------------------------------------------
// main fused kernel: 1 block = 128 points, 4 waves in 2x2 tile grid
// ------------------------------------------------------------------
template <int KT>
__device__ __forceinline__ void mlp_layer(ushort_t* s_act,
                                          const ushort_t* __restrict__ wsW,
                                          const ushort_t* __restrict__ bias,
                                          int wrow, int wcol, int lane) {
  f32x4 acc[4][8] = {};
  const int m0 = lane & 15;
  const int q = lane >> 4;
#pragma unroll
  for (int kt = 0; kt < KT; ++kt) {
    bf16x8 a[4], b[8];
#pragma unroll
    for (int t = 0; t < 4; ++t) {
      int row = wrow * 64 + t * 16 + m0;
      int addr = row * 256 + (((kt * 4 + q) ^ (row & 31)) << 3);
      union { uint4 u; bf16x8 v; } tmp;
      tmp.u = *(const uint4*)(s_act + addr);
      a[t] = tmp.v;
    }
#pragma unroll
    for (int c = 0; c < 8; ++c) {
      union { uint4 u; bf16x8 v; } tmp;
      tmp.u = *(const uint4*)(wsW + ((size_t)((kt * 16 + wcol * 8 + c) * 64 + lane) * 8));
      b[c] = tmp.v;
    }
#pragma unroll
    for (int t = 0; t < 4; ++t)
#pragma unroll
      for (int c = 0; c < 8; ++c)
        acc[t][c] = __builtin_amdgcn_mfma_f32_16x16x32_bf16(a[t], b[c], acc[t][c], 0, 0, 0);
  }
  __syncthreads();   // all waves done reading act
#pragma unroll
  for (int c = 0; c < 8; ++c) {
    int col = wcol * 128 + c * 16 + m0;
    float bf = bf2f(bias[col]);
#pragma unroll
    for (int t = 0; t < 4; ++t) {
#pragma unroll
      for (int r = 0; r < 4; ++r) {
        float v = acc[t][c][r] + bf;
        v = fmaxf(v, 0.0f);
        int row = wrow * 64 + t * 16 + q * 4 + r;
        s_act[act_addr(row, col)] = f2bf(v);
      }
    }
  }
  __syncthreads();   // act ready for next layer
}

__global__ __launch_bounds__(256, 2)
void tensorf_main(const void* __restrict__ x,
                  const ushort_t* __restrict__ ws,
                  void* __restrict__ out) {
  __shared__ ushort_t s_act[128 * 256];   // 64 KB, XOR-swizzled
  const int isbf = (int)((const uint_t*)ws)[0];
  const int tid = threadIdx.x;
  const int lane = tid & 63;
  const int wid = tid >> 6;
  const int wrow = wid >> 1, wcol = wid & 1;
  const int blk = blockIdx.x;

  // ---- Phase A: features + positional encoding into s_act[:, 0:64] ----
  {
    int pl = tid & 127;
    int task = tid >> 7;          // threads 0-127: gather+x+pad; 128-255: sin/cos
    long p = (long)blk * 128 + pl;
    float x0 = ldf(x, p * 3 + 0, isbf);
    float x1 = ldf(x, p * 3 + 1, isbf);
    float x2 = ldf(x, p * 3 + 2, isbf);
    if (task == 0) {
      // match np: idx = trunc((x+1.0)*0.5*127), clip to [0,127]
      int ix = (int)(((x0 + 1.0f) * 0.5f) * 127.0f);
      int iy = (int)(((x1 + 1.0f) * 0.5f) * 127.0f);
      int iz = (int)(((x2 + 1.0f) * 0.5f) * 127.0f);
      ix = ix < 0 ? 0 : (ix > 127 ? 127 : ix);
      iy = iy < 0 ? 0 : (iy > 127 ? 127 : iy);
      iz = iz < 0 ? 0 : (iz > 127 ? 127 : iz);
      union { uint4 u; ushort_t s[8]; } a, b, c;
      a.u = *(const uint4*)(ws + OFF_PL + (size_t)(iy * 128 + ix) * 8);
      b.u = *(const uint4*)(ws + OFF_PL + 131072 + (size_t)(iz * 128 + ix) * 8);
      c.u = *(const uint4*)(ws + OFF_PL + 262144 + (size_t)(iz * 128 + iy) * 8);
#pragma unroll
      for (int r = 0; r < 8; ++r) {
        float f = bf2f(a.s[r]) + bf2f(b.s[r]) + bf2f(c.s[r]);
        s_act[act_addr(pl, r)] = f2bf(f);
      }
      s_act[act_addr(pl, 8)]  = f2bf(x0);
      s_act[act_addr(pl, 9)]  = f2bf(x1);
      s_act[act_addr(pl, 10)] = f2bf(x2);
#pragma unroll
      for (int k = 47; k < 64; ++k) s_act[act_addr(pl, k)] = 0;
    } else {
      float fx[3] = { x0, x1, x2 };
#pragma unroll
      for (int l = 0; l < 6; ++l) {
        float fr = (float)(1 << l);
#pragma unroll
        for (int d = 0; d < 3; ++d) {
          float ang = fx[d] * fr;
          s_act[act_addr(pl, 11 + l * 6 + d)]     = f2bf(__sinf(ang));
          s_act[act_addr(pl, 11 + l * 6 + 3 + d)] = f2bf(__cosf(ang));
        }
      }
    }
  }
  __syncthreads();

  mlp_layer<2>(s_act, ws + OFF_W0, ws + OFF_B0, wrow, wcol, lane);
  mlp_layer<8>(s_act, ws + OFF_W1, ws + OFF_B1, wrow, wcol, lane);
  mlp_layer<8>(s_act, ws + OFF_W2, ws + OFF_B2, wrow, wcol, lane);
  mlp_layer<8>(s_act, ws + OFF_W3, ws + OFF_B3, wrow, wcol, lane);

  // ---- head: [128x256] @ [256x16]; each wave does 32 rows ----
  {
    f32x4 acc[2] = {};
    const int m0 = lane & 15;
    const int q = lane >> 4;
    const ushort_t* wh = ws + OFF_WH;
#pragma unroll
    for (int kt = 0; kt < 8; ++kt) {
      union { uint4 u; bf16x8 v; } tb;
      tb.u = *(const uint4*)(wh + ((size_t)(kt * 64 + lane) * 8));
#pragma unroll
      for (int t = 0; t < 2; ++t) {
        int row = wid * 32 + t * 16 + m0;
        int addr = row * 256 + (((kt * 4 + q) ^ (row & 31)) << 3);
        union { uint4 u; bf16x8 v; } ta;
        ta.u = *(const uint4*)(s_act + addr);
        acc[t] = __builtin_amdgcn_mfma_f32_16x16x32_bf16(ta.v, tb.v, acc[t], 0, 0, 0);
      }
    }
    float br0 = bf2f(ws[OFF_BRGB + 0]), br1 = bf2f(ws[OFF_BRGB + 1]), br2 = bf2f(ws[OFF_BRGB + 2]);
    float bs = bf2f(ws[OFF_BSIG]);
    int col = lane & 15;
#pragma unroll
    for (int t = 0; t < 2; ++t) {
#pragma unroll
      for (int r = 0; r < 4; ++r) {
        int row = wid * 32 + t * 16 + q * 4 + r;
        long p = (long)blk * 128 + row;
        float v = acc[t][r];
        if (col == 3) {
          float z = v + bs;
          float sp = (z > 20.0f) ? z : __logf(1.0f + __expf(z));
          stf(out, (long)3 * NPTS + p, isbf, sp);
        } else if (col < 3) {
          float z = v + (col == 0 ? br0 : (col == 1 ? br1 : br2));
          float sg = 1.0f / (1.0f + __expf(-z));
          stf(out, p * 3 + col, isbf, sg);
        }
      }
    }
  }
}

extern "C" void kernel_launch(void* const* d_in, const int* in_sizes, int n_in,
                              void* d_out, int out_size, void* d_ws, size_t ws_size,
                              hipStream_t stream) {
  const void* x    = d_in[0];
  const void* fxy  = d_in[1];
  const void* fxz  = d_in[2];
  const void* fyz  = d_in[3];
  const void* W0   = d_in[4];
  const void* b0   = d_in[5];
  const void* W1   = d_in[6];
  const void* b1   = d_in[7];
  const void* W2   = d_in[8];
  const void* b2   = d_in[9];
  const void* W3   = d_in[10];
  const void* b3   = d_in[11];
  const void* Wsig = d_in[12];
  const void* bsig = d_in[13];
  const void* Wrgb = d_in[14];
  const void* brgb = d_in[15];
  ushort_t* ws = (ushort_t*)d_ws;

  hipLaunchKernelGGL(sniff_dtype, dim3(1), dim3(64), 0, stream, fxy, ws);
  hipLaunchKernelGGL(prep_bias, dim3(1), dim3(256), 0, stream,
                     b0, b1, b2, b3, bsig, brgb, ws);
  hipLaunchKernelGGL(prep_weights, dim3(106), dim3(256), 0, stream,
                     W0, W1, W2, W3, Wsig, Wrgb, ws);
  hipLaunchKernelGGL(prep_planes, dim3(192), dim3(256), 0, stream,
                     fxy, fxz, fyz, ws);
  hipLaunchKernelGGL(tensorf_main, dim3(8192), dim3(256), 0, stream,
                     x, ws, d_out);
}

// Round 3
// 1362.680 us; speedup vs baseline: 1.1997x; 1.1997x over previous
//
#include <hip/hip_runtime.h>

typedef unsigned short ushort_t;
typedef unsigned int uint_t;

typedef __bf16 bf16x8 __attribute__((ext_vector_type(8)));
typedef float f32x4 __attribute__((ext_vector_type(4)));

#define NPTS (1 << 20)

// ---- ws layout (ushort units) ----
#define OFF_FLAG 0        // uint flag at ws[0..1]: 1 = inputs are bf16, 0 = fp32
#define OFF_B0   16
#define OFF_B1   272
#define OFF_B2   528
#define OFF_B3   784
#define OFF_BSIG 1040
#define OFF_BRGB 1041
#define OFF_W0   1056     // K=64 (47 padded), N=256: 32 tiles * 512
#define OFF_W1   17440    // K=256,N=256: 128 tiles * 512
#define OFF_W2   82976
#define OFF_W3   148512
#define OFF_WH   214048   // K=256,N=16 (rgb0,rgb1,rgb2,sig,0...): 8 tiles * 512
#define OFF_PL   218144   // transposed planes [plane][pos(16384)][rank(8)]

__device__ __forceinline__ float bf2f(ushort_t u) {
  union { uint_t i; float f; } c; c.i = ((uint_t)u) << 16; return c.f;
}
__device__ __forceinline__ ushort_t f2bf(float f) {
  union { float f; uint_t i; } c; c.f = f;
  uint_t x = c.i;
  return (ushort_t)((x + 0x7fffu + ((x >> 16) & 1u)) >> 16);
}
// dtype-branched scalar loads
__device__ __forceinline__ float ldf(const void* p, long i, int isbf) {
  return isbf ? bf2f(((const ushort_t*)p)[i]) : ((const float*)p)[i];
}
__device__ __forceinline__ ushort_t ldbf(const void* p, long i, int isbf) {
  return isbf ? ((const ushort_t*)p)[i] : f2bf(((const float*)p)[i]);
}
__device__ __forceinline__ void stf(void* p, long i, int isbf, float v) {
  if (isbf) ((ushort_t*)p)[i] = f2bf(v);
  else      ((float*)p)[i] = v;
}

// XOR-swizzled LDS activation address (row-major 128 x 256 bf16, 16B-group swizzle)
__device__ __forceinline__ int act_addr(int row, int k) {
  return row * 256 + ((((k >> 3) ^ (row & 31)) << 3) | (k & 7));
}

// ------------------------------------------------------------------
// sniff: decide whether inputs are stored as bf16 or fp32.
// ------------------------------------------------------------------
__global__ void sniff_dtype(const void* __restrict__ f, ushort_t* __restrict__ ws) {
  __shared__ int s_cnt;
  if (threadIdx.x == 0) s_cnt = 0;
  __syncthreads();
  const ushort_t* u = (const ushort_t*)f;
  int c = 0;
  for (int j = 0; j < 4; ++j) {
    ushort_t v = u[(threadIdx.x * 4 + j) * 2];
    int e = (v >> 7) & 0xFF;
    if (e > 100 && e < 140) ++c;
  }
  atomicAdd(&s_cnt, c);
  __syncthreads();
  if (threadIdx.x == 0) ((uint_t*)ws)[0] = (s_cnt >= 160) ? 1u : 0u;
}

__global__ void prep_bias(const void* __restrict__ b0, const void* __restrict__ b1,
                          const void* __restrict__ b2, const void* __restrict__ b3,
                          const void* __restrict__ bsig, const void* __restrict__ brgb,
                          ushort_t* __restrict__ ws) {
  const int isbf = (int)((const uint_t*)ws)[0];
  int i = threadIdx.x;
  ws[OFF_B0 + i] = ldbf(b0, i, isbf);
  ws[OFF_B1 + i] = ldbf(b1, i, isbf);
  ws[OFF_B2 + i] = ldbf(b2, i, isbf);
  ws[OFF_B3 + i] = ldbf(b3, i, isbf);
  if (i == 0) ws[OFF_BSIG] = ldbf(bsig, 0, isbf);
  if (i < 3) ws[OFF_BRGB + i] = ldbf(brgb, i, isbf);
}

// ------------------------------------------------------------------
// prep: swizzle weights into MFMA B-fragment-native layout
// ------------------------------------------------------------------
__global__ void prep_weights(const void* __restrict__ W0,
                             const void* __restrict__ W1,
                             const void* __restrict__ W2,
                             const void* __restrict__ W3,
                             const void* __restrict__ Wsig,
                             const void* __restrict__ Wrgb,
                             ushort_t* __restrict__ ws) {
  const int isbf = (int)((const uint_t*)ws)[0];
  int t = blockIdx.x * 256 + threadIdx.x;   // 424 tiles * 64 lanes = 27136
  int lane = t & 63;
  int tile = t >> 6;
  const void* src = nullptr;
  ushort_t* dst;
  int kt, nt, Ksrc = 256;
  bool head = false;
  if (tile < 32) {            // L0: 47x256 padded to 64x256
    kt = tile >> 4; nt = tile & 15; src = W0; Ksrc = 47;
    dst = ws + OFF_W0 + (size_t)tile * 512;
  } else if (tile < 160) {
    int tl = tile - 32; kt = tl >> 4; nt = tl & 15; src = W1;
    dst = ws + OFF_W1 + (size_t)tl * 512;
  } else if (tile < 288) {
    int tl = tile - 160; kt = tl >> 4; nt = tl & 15; src = W2;
    dst = ws + OFF_W2 + (size_t)tl * 512;
  } else if (tile < 416) {
    int tl = tile - 288; kt = tl >> 4; nt = tl & 15; src = W3;
    dst = ws + OFF_W3 + (size_t)tl * 512;
  } else {                    // head: cols 0..2 = W_rgb, col 3 = W_sig
    int tl = tile - 416; kt = tl; nt = 0; head = true;
    dst = ws + OFF_WH + (size_t)tl * 512;
  }
  int n = nt * 16 + (lane & 15);
  int kb = kt * 32 + (lane >> 4) * 8;
  for (int i = 0; i < 8; ++i) {
    int k = kb + i;
    ushort_t v = 0;
    if (head) {
      if (n < 3) v = ldbf(Wrgb, (long)k * 3 + n, isbf);
      else if (n == 3) v = ldbf(Wsig, k, isbf);
    } else if (k < Ksrc) {
      v = ldbf(src, (long)k * 256 + n, isbf);
    }
    dst[lane * 8 + i] = v;
  }
}

// transpose planes from [rank][pos] to [pos][rank]
__global__ void prep_planes(const void* __restrict__ fxy,
                            const void* __restrict__ fxz,
                            const void* __restrict__ fyz,
                            ushort_t* __restrict__ ws) {
  const int isbf = (int)((const uint_t*)ws)[0];
  int t = blockIdx.x * 256 + threadIdx.x;   // 3*16384 = 49152
  int plane = t >> 14, pos = t & 16383;
  const void* src = (plane == 0) ? fxy : (plane == 1) ? fxz : fyz;
  ushort_t* d = ws + OFF_PL + (size_t)plane * 131072 + (size_t)pos * 8;
  for (int r = 0; r < 8; ++r) d[r] = ldbf(src, (long)r * 16384 + pos, isbf);
}

// ------------------------------------------------------------------
// main fused kernel: 1 block = 128 points, 8 waves in 2x4 tile grid
// (64x64 per wave -> acc = 4x4 f32x4 = 64 VGPRs, no spill at 128-reg cap)
// ------------------------------------------------------------------
template <int KT>
__device__ __forceinline__ void mlp_layer(ushort_t* s_act,
                                          const ushort_t* __restrict__ wsW,
                                          const ushort_t* __restrict__ bias,
                                          int wrow, int wcol, int lane) {
  f32x4 acc[4][4] = {};
  const int m0 = lane & 15;
  const int q = lane >> 4;
#pragma unroll
  for (int kt = 0; kt < KT; ++kt) {
    bf16x8 a[4], b[4];
#pragma unroll
    for (int t = 0; t < 4; ++t) {
      int row = wrow * 64 + t * 16 + m0;
      int addr = row * 256 + (((kt * 4 + q) ^ (row & 31)) << 3);
      union { uint4 u; bf16x8 v; } tmp;
      tmp.u = *(const uint4*)(s_act + addr);
      a[t] = tmp.v;
    }
#pragma unroll
    for (int c = 0; c < 4; ++c) {
      int nt = wcol * 4 + c;
      union { uint4 u; bf16x8 v; } tmp;
      tmp.u = *(const uint4*)(wsW + ((size_t)((kt * 16 + nt) * 64 + lane) * 8));
      b[c] = tmp.v;
    }
#pragma unroll
    for (int t = 0; t < 4; ++t)
#pragma unroll
      for (int c = 0; c < 4; ++c)
        acc[t][c] = __builtin_amdgcn_mfma_f32_16x16x32_bf16(a[t], b[c], acc[t][c], 0, 0, 0);
  }
  __syncthreads();   // all waves done reading act
#pragma unroll
  for (int c = 0; c < 4; ++c) {
    int col = wcol * 64 + c * 16 + m0;
    float bf = bf2f(bias[col]);
#pragma unroll
    for (int t = 0; t < 4; ++t) {
#pragma unroll
      for (int r = 0; r < 4; ++r) {
        float v = acc[t][c][r] + bf;
        v = fmaxf(v, 0.0f);
        int row = wrow * 64 + t * 16 + q * 4 + r;
        s_act[act_addr(row, col)] = f2bf(v);
      }
    }
  }
  __syncthreads();   // act ready for next layer
}

__global__ __launch_bounds__(512, 4)
void tensorf_main(const void* __restrict__ x,
                  const ushort_t* __restrict__ ws,
                  void* __restrict__ out) {
  __shared__ ushort_t s_act[128 * 256];   // 64 KB, XOR-swizzled
  const int isbf = (int)((const uint_t*)ws)[0];
  const int tid = threadIdx.x;
  const int lane = tid & 63;
  const int wid = tid >> 6;        // 0..7
  const int wrow = wid >> 2;       // 0..1
  const int wcol = wid & 3;        // 0..3
  const int blk = blockIdx.x;

  // ---- Phase A: features + positional encoding into s_act[:, 0:64] ----
  // 4 threads per point: s=0 gather+x, s=1..3 trig windows of 12 cols
  {
    int pl = tid >> 2;            // 0..127
    int s = tid & 3;
    long p = (long)blk * 128 + pl;
    float x0 = ldf(x, p * 3 + 0, isbf);
    float x1 = ldf(x, p * 3 + 1, isbf);
    float x2 = ldf(x, p * 3 + 2, isbf);
    if (s == 0) {
      // match np: idx = trunc((x+1.0)*0.5*127), clip to [0,127]
      int ix = (int)(((x0 + 1.0f) * 0.5f) * 127.0f);
      int iy = (int)(((x1 + 1.0f) * 0.5f) * 127.0f);
      int iz = (int)(((x2 + 1.0f) * 0.5f) * 127.0f);
      ix = ix < 0 ? 0 : (ix > 127 ? 127 : ix);
      iy = iy < 0 ? 0 : (iy > 127 ? 127 : iy);
      iz = iz < 0 ? 0 : (iz > 127 ? 127 : iz);
      union { uint4 u; ushort_t s[8]; } a, b, c;
      a.u = *(const uint4*)(ws + OFF_PL + (size_t)(iy * 128 + ix) * 8);
      b.u = *(const uint4*)(ws + OFF_PL + 131072 + (size_t)(iz * 128 + ix) * 8);
      c.u = *(const uint4*)(ws + OFF_PL + 262144 + (size_t)(iz * 128 + iy) * 8);
#pragma unroll
      for (int r = 0; r < 8; ++r) {
        float f = bf2f(a.s[r]) + bf2f(b.s[r]) + bf2f(c.s[r]);
        s_act[act_addr(pl, r)] = f2bf(f);
      }
      s_act[act_addr(pl, 8)]  = f2bf(x0);
      s_act[act_addr(pl, 9)]  = f2bf(x1);
      s_act[act_addr(pl, 10)] = f2bf(x2);
#pragma unroll
      for (int k = 47; k < 64; ++k) s_act[act_addr(pl, k)] = 0;
    } else {
      float fx[3] = { x0, x1, x2 };
      int k0 = 11 + (s - 1) * 12;
#pragma unroll
      for (int j = 0; j < 12; ++j) {
        int k = k0 + j;
        int jj = k - 11;
        int l = jj / 6, rem = jj % 6;
        float ang = fx[rem % 3] * (float)(1 << l);
        float v = (rem < 3) ? __sinf(ang) : __cosf(ang);
        s_act[act_addr(pl, k)] = f2bf(v);
      }
    }
  }
  __syncthreads();

  mlp_layer<2>(s_act, ws + OFF_W0, ws + OFF_B0, wrow, wcol, lane);
  mlp_layer<8>(s_act, ws + OFF_W1, ws + OFF_B1, wrow, wcol, lane);
  mlp_layer<8>(s_act, ws + OFF_W2, ws + OFF_B2, wrow, wcol, lane);
  mlp_layer<8>(s_act, ws + OFF_W3, ws + OFF_B3, wrow, wcol, lane);

  // ---- head: [128x256] @ [256x16]; each wave does 16 rows ----
  {
    f32x4 acc = {};
    const int m0 = lane & 15;
    const int q = lane >> 4;
    const ushort_t* wh = ws + OFF_WH;
#pragma unroll
    for (int kt = 0; kt < 8; ++kt) {
      union { uint4 u; bf16x8 v; } tb;
      tb.u = *(const uint4*)(wh + ((size_t)(kt * 64 + lane) * 8));
      int row = wid * 16 + m0;
      int addr = row * 256 + (((kt * 4 + q) ^ (row & 31)) << 3);
      union { uint4 u; bf16x8 v; } ta;
      ta.u = *(const uint4*)(s_act + addr);
      acc = __builtin_amdgcn_mfma_f32_16x16x32_bf16(ta.v, tb.v, acc, 0, 0, 0);
    }
    float br0 = bf2f(ws[OFF_BRGB + 0]), br1 = bf2f(ws[OFF_BRGB + 1]), br2 = bf2f(ws[OFF_BRGB + 2]);
    float bs = bf2f(ws[OFF_BSIG]);
    int col = lane & 15;
#pragma unroll
    for (int r = 0; r < 4; ++r) {
      int row = wid * 16 + q * 4 + r;
      long p = (long)blk * 128 + row;
      float v = acc[r];
      if (col == 3) {
        float z = v + bs;
        float sp = (z > 20.0f) ? z : __logf(1.0f + __expf(z));
        stf(out, (long)3 * NPTS + p, isbf, sp);
      } else if (col < 3) {
        float z = v + (col == 0 ? br0 : (col == 1 ? br1 : br2));
        float sg = 1.0f / (1.0f + __expf(-z));
        stf(out, p * 3 + col, isbf, sg);
      }
    }
  }
}

extern "C" void kernel_launch(void* const* d_in, const int* in_sizes, int n_in,
                              void* d_out, int out_size, void* d_ws, size_t ws_size,
                              hipStream_t stream) {
  const void* x    = d_in[0];
  const void* fxy  = d_in[1];
  const void* fxz  = d_in[2];
  const void* fyz  = d_in[3];
  const void* W0   = d_in[4];
  const void* b0   = d_in[5];
  const void* W1   = d_in[6];
  const void* b1   = d_in[7];
  const void* W2   = d_in[8];
  const void* b2   = d_in[9];
  const void* W3   = d_in[10];
  const void* b3   = d_in[11];
  const void* Wsig = d_in[12];
  const void* bsig = d_in[13];
  const void* Wrgb = d_in[14];
  const void* brgb = d_in[15];
  ushort_t* ws = (ushort_t*)d_ws;

  hipLaunchKernelGGL(sniff_dtype, dim3(1), dim3(64), 0, stream, fxy, ws);
  hipLaunchKernelGGL(prep_bias, dim3(1), dim3(256), 0, stream,
                     b0, b1, b2, b3, bsig, brgb, ws);
  hipLaunchKernelGGL(prep_weights, dim3(106), dim3(256), 0, stream,
                     W0, W1, W2, W3, Wsig, Wrgb, ws);
  hipLaunchKernelGGL(prep_planes, dim3(192), dim3(256), 0, stream,
                     fxy, fxz, fyz, ws);
  hipLaunchKernelGGL(tensorf_main, dim3(8192), dim3(512), 0, stream,
                     x, ws, d_out);
}

// Round 4
// 675.292 us; speedup vs baseline: 2.4209x; 2.0179x over previous
//
#include <hip/hip_runtime.h>

typedef unsigned short ushort_t;
typedef unsigned int uint_t;

typedef __bf16 bf16x8 __attribute__((ext_vector_type(8)));
typedef float f32x4 __attribute__((ext_vector_type(4)));

#define NPTS (1 << 20)

// ---- ws layout (ushort units) ----
#define OFF_FLAG 0        // uint flag at ws[0..1]: 1 = inputs are bf16, 0 = fp32
#define OFF_B0   16
#define OFF_B1   272
#define OFF_B2   528
#define OFF_B3   784
#define OFF_BSIG 1040
#define OFF_BRGB 1041
#define OFF_W0   1056     // K=64 (47 padded), N=256: 32 tiles * 512
#define OFF_W1   17440    // K=256,N=256: 128 tiles * 512
#define OFF_W2   82976
#define OFF_W3   148512
#define OFF_WH   214048   // K=256,N=16 (rgb0,rgb1,rgb2,sig,0...): 8 tiles * 512
#define OFF_PL   218144   // transposed planes [plane][pos(16384)][rank(8)]

__device__ __forceinline__ float bf2f(ushort_t u) {
  union { uint_t i; float f; } c; c.i = ((uint_t)u) << 16; return c.f;
}
__device__ __forceinline__ ushort_t f2bf(float f) {
  union { float f; uint_t i; } c; c.f = f;
  uint_t x = c.i;
  return (ushort_t)((x + 0x7fffu + ((x >> 16) & 1u)) >> 16);
}
// dtype-branched scalar loads
__device__ __forceinline__ float ldf(const void* p, long i, int isbf) {
  return isbf ? bf2f(((const ushort_t*)p)[i]) : ((const float*)p)[i];
}
__device__ __forceinline__ ushort_t ldbf(const void* p, long i, int isbf) {
  return isbf ? ((const ushort_t*)p)[i] : f2bf(((const float*)p)[i]);
}
__device__ __forceinline__ void stf(void* p, long i, int isbf, float v) {
  if (isbf) ((ushort_t*)p)[i] = f2bf(v);
  else      ((float*)p)[i] = v;
}

// XOR-swizzled LDS activation address (row-major 128 x 256 bf16, 16B-group swizzle)
__device__ __forceinline__ int act_addr(int row, int k) {
  return row * 256 + ((((k >> 3) ^ (row & 31)) << 3) | (k & 7));
}

// ------------------------------------------------------------------
// sniff: decide whether inputs are stored as bf16 or fp32.
// ------------------------------------------------------------------
__global__ void sniff_dtype(const void* __restrict__ f, ushort_t* __restrict__ ws) {
  __shared__ int s_cnt;
  if (threadIdx.x == 0) s_cnt = 0;
  __syncthreads();
  const ushort_t* u = (const ushort_t*)f;
  int c = 0;
  for (int j = 0; j < 4; ++j) {
    ushort_t v = u[(threadIdx.x * 4 + j) * 2];
    int e = (v >> 7) & 0xFF;
    if (e > 100 && e < 140) ++c;
  }
  atomicAdd(&s_cnt, c);
  __syncthreads();
  if (threadIdx.x == 0) ((uint_t*)ws)[0] = (s_cnt >= 160) ? 1u : 0u;
}

__global__ void prep_bias(const void* __restrict__ b0, const void* __restrict__ b1,
                          const void* __restrict__ b2, const void* __restrict__ b3,
                          const void* __restrict__ bsig, const void* __restrict__ brgb,
                          ushort_t* __restrict__ ws) {
  const int isbf = (int)((const uint_t*)ws)[0];
  int i = threadIdx.x;
  ws[OFF_B0 + i] = ldbf(b0, i, isbf);
  ws[OFF_B1 + i] = ldbf(b1, i, isbf);
  ws[OFF_B2 + i] = ldbf(b2, i, isbf);
  ws[OFF_B3 + i] = ldbf(b3, i, isbf);
  if (i == 0) ws[OFF_BSIG] = ldbf(bsig, 0, isbf);
  if (i < 3) ws[OFF_BRGB + i] = ldbf(brgb, i, isbf);
}

// ------------------------------------------------------------------
// prep: swizzle weights into MFMA B-fragment-native layout
// ------------------------------------------------------------------
__global__ void prep_weights(const void* __restrict__ W0,
                             const void* __restrict__ W1,
                             const void* __restrict__ W2,
                             const void* __restrict__ W3,
                             const void* __restrict__ Wsig,
                             const void* __restrict__ Wrgb,
                             ushort_t* __restrict__ ws) {
  const int isbf = (int)((const uint_t*)ws)[0];
  int t = blockIdx.x * 256 + threadIdx.x;   // 424 tiles * 64 lanes = 27136
  int lane = t & 63;
  int tile = t >> 6;
  const void* src = nullptr;
  ushort_t* dst;
  int kt, nt, Ksrc = 256;
  bool head = false;
  if (tile < 32) {            // L0: 47x256 padded to 64x256
    kt = tile >> 4; nt = tile & 15; src = W0; Ksrc = 47;
    dst = ws + OFF_W0 + (size_t)tile * 512;
  } else if (tile < 160) {
    int tl = tile - 32; kt = tl >> 4; nt = tl & 15; src = W1;
    dst = ws + OFF_W1 + (size_t)tl * 512;
  } else if (tile < 288) {
    int tl = tile - 160; kt = tl >> 4; nt = tl & 15; src = W2;
    dst = ws + OFF_W2 + (size_t)tl * 512;
  } else if (tile < 416) {
    int tl = tile - 288; kt = tl >> 4; nt = tl & 15; src = W3;
    dst = ws + OFF_W3 + (size_t)tl * 512;
  } else {                    // head: cols 0..2 = W_rgb, col 3 = W_sig
    int tl = tile - 416; kt = tl; nt = 0; head = true;
    dst = ws + OFF_WH + (size_t)tl * 512;
  }
  int n = nt * 16 + (lane & 15);
  int kb = kt * 32 + (lane >> 4) * 8;
  for (int i = 0; i < 8; ++i) {
    int k = kb + i;
    ushort_t v = 0;
    if (head) {
      if (n < 3) v = ldbf(Wrgb, (long)k * 3 + n, isbf);
      else if (n == 3) v = ldbf(Wsig, k, isbf);
    } else if (k < Ksrc) {
      v = ldbf(src, (long)k * 256 + n, isbf);
    }
    dst[lane * 8 + i] = v;
  }
}

// transpose planes from [rank][pos] to [pos][rank]
__global__ void prep_planes(const void* __restrict__ fxy,
                            const void* __restrict__ fxz,
                            const void* __restrict__ fyz,
                            ushort_t* __restrict__ ws) {
  const int isbf = (int)((const uint_t*)ws)[0];
  int t = blockIdx.x * 256 + threadIdx.x;   // 3*16384 = 49152
  int plane = t >> 14, pos = t & 16383;
  const void* src = (plane == 0) ? fxy : (plane == 1) ? fxz : fyz;
  ushort_t* d = ws + OFF_PL + (size_t)plane * 131072 + (size_t)pos * 8;
  for (int r = 0; r < 8; ++r) d[r] = ldbf(src, (long)r * 16384 + pos, isbf);
}

// ------------------------------------------------------------------
// main fused kernel: 1 block = 128 points, 8 waves in 2x4 tile grid.
// kt loop is NOT unrolled: acc (64 AGPR) + a/b (32 VGPR) must stay
// within the 128-reg wave budget of __launch_bounds__(512,4); full
// unroll hoists loads across kt and spills ~190 KB/block to scratch
// (round-3 counters: 1.5 GB phantom WRITE_SIZE).
// ------------------------------------------------------------------
template <int KT>
__device__ void mlp_layer(ushort_t* s_act,
                          const ushort_t* __restrict__ wsW,
                          const ushort_t* __restrict__ bias,
                          int wrow, int wcol, int lane) {
  f32x4 acc[4][4] = {};
  const int m0 = lane & 15;
  const int q = lane >> 4;
#pragma unroll 1
  for (int kt = 0; kt < KT; ++kt) {
    bf16x8 a[4], b[4];
#pragma unroll
    for (int t = 0; t < 4; ++t) {
      int row = wrow * 64 + t * 16 + m0;
      int addr = row * 256 + (((kt * 4 + q) ^ (row & 31)) << 3);
      union { uint4 u; bf16x8 v; } tmp;
      tmp.u = *(const uint4*)(s_act + addr);
      a[t] = tmp.v;
    }
#pragma unroll
    for (int c = 0; c < 4; ++c) {
      int nt = wcol * 4 + c;
      union { uint4 u; bf16x8 v; } tmp;
      tmp.u = *(const uint4*)(wsW + ((size_t)((kt * 16 + nt) * 64 + lane) * 8));
      b[c] = tmp.v;
    }
#pragma unroll
    for (int t = 0; t < 4; ++t)
#pragma unroll
      for (int c = 0; c < 4; ++c)
        acc[t][c] = __builtin_amdgcn_mfma_f32_16x16x32_bf16(a[t], b[c], acc[t][c], 0, 0, 0);
  }
  __syncthreads();   // all waves done reading act
#pragma unroll
  for (int c = 0; c < 4; ++c) {
    int col = wcol * 64 + c * 16 + m0;
    float bf = bf2f(bias[col]);
#pragma unroll
    for (int t = 0; t < 4; ++t) {
#pragma unroll
      for (int r = 0; r < 4; ++r) {
        float v = acc[t][c][r] + bf;
        v = fmaxf(v, 0.0f);
        int row = wrow * 64 + t * 16 + q * 4 + r;
        s_act[act_addr(row, col)] = f2bf(v);
      }
    }
  }
  __syncthreads();   // act ready for next layer
}

__global__ __launch_bounds__(512, 4)
void tensorf_main(const void* __restrict__ x,
                  const ushort_t* __restrict__ ws,
                  void* __restrict__ out) {
  __shared__ ushort_t s_act[128 * 256];   // 64 KB, XOR-swizzled
  const int isbf = (int)((const uint_t*)ws)[0];
  const int tid = threadIdx.x;
  const int lane = tid & 63;
  const int wid = tid >> 6;        // 0..7
  const int wrow = wid >> 2;       // 0..1
  const int wcol = wid & 3;        // 0..3
  const int blk = blockIdx.x;

  // ---- Phase A: features + positional encoding into s_act[:, 0:64] ----
  // 4 threads per point: s=0 gather+x, s=1..3 trig windows of 12 cols
  {
    int pl = tid >> 2;            // 0..127
    int s = tid & 3;
    long p = (long)blk * 128 + pl;
    float x0 = ldf(x, p * 3 + 0, isbf);
    float x1 = ldf(x, p * 3 + 1, isbf);
    float x2 = ldf(x, p * 3 + 2, isbf);
    if (s == 0) {
      // match np: idx = trunc((x+1.0)*0.5*127), clip to [0,127]
      int ix = (int)(((x0 + 1.0f) * 0.5f) * 127.0f);
      int iy = (int)(((x1 + 1.0f) * 0.5f) * 127.0f);
      int iz = (int)(((x2 + 1.0f) * 0.5f) * 127.0f);
      ix = ix < 0 ? 0 : (ix > 127 ? 127 : ix);
      iy = iy < 0 ? 0 : (iy > 127 ? 127 : iy);
      iz = iz < 0 ? 0 : (iz > 127 ? 127 : iz);
      union { uint4 u; ushort_t s[8]; } a, b, c;
      a.u = *(const uint4*)(ws + OFF_PL + (size_t)(iy * 128 + ix) * 8);
      b.u = *(const uint4*)(ws + OFF_PL + 131072 + (size_t)(iz * 128 + ix) * 8);
      c.u = *(const uint4*)(ws + OFF_PL + 262144 + (size_t)(iz * 128 + iy) * 8);
#pragma unroll
      for (int r = 0; r < 8; ++r) {
        float f = bf2f(a.s[r]) + bf2f(b.s[r]) + bf2f(c.s[r]);
        s_act[act_addr(pl, r)] = f2bf(f);
      }
      s_act[act_addr(pl, 8)]  = f2bf(x0);
      s_act[act_addr(pl, 9)]  = f2bf(x1);
      s_act[act_addr(pl, 10)] = f2bf(x2);
#pragma unroll
      for (int k = 47; k < 64; ++k) s_act[act_addr(pl, k)] = 0;
    } else {
      float fx[3] = { x0, x1, x2 };
      int k0 = 11 + (s - 1) * 12;
#pragma unroll
      for (int j = 0; j < 12; ++j) {
        int k = k0 + j;
        int jj = k - 11;
        int l = jj / 6, rem = jj % 6;
        float ang = fx[rem % 3] * (float)(1 << l);
        float v = (rem < 3) ? __sinf(ang) : __cosf(ang);
        s_act[act_addr(pl, k)] = f2bf(v);
      }
    }
  }
  __syncthreads();

  mlp_layer<2>(s_act, ws + OFF_W0, ws + OFF_B0, wrow, wcol, lane);
  mlp_layer<8>(s_act, ws + OFF_W1, ws + OFF_B1, wrow, wcol, lane);
  mlp_layer<8>(s_act, ws + OFF_W2, ws + OFF_B2, wrow, wcol, lane);
  mlp_layer<8>(s_act, ws + OFF_W3, ws + OFF_B3, wrow, wcol, lane);

  // ---- head: [128x256] @ [256x16]; each wave does 16 rows ----
  {
    f32x4 acc = {};
    const int m0 = lane & 15;
    const int q = lane >> 4;
    const ushort_t* wh = ws + OFF_WH;
#pragma unroll
    for (int kt = 0; kt < 8; ++kt) {
      union { uint4 u; bf16x8 v; } tb;
      tb.u = *(const uint4*)(wh + ((size_t)(kt * 64 + lane) * 8));
      int row = wid * 16 + m0;
      int addr = row * 256 + (((kt * 4 + q) ^ (row & 31)) << 3);
      union { uint4 u; bf16x8 v; } ta;
      ta.u = *(const uint4*)(s_act + addr);
      acc = __builtin_amdgcn_mfma_f32_16x16x32_bf16(ta.v, tb.v, acc, 0, 0, 0);
    }
    float br0 = bf2f(ws[OFF_BRGB + 0]), br1 = bf2f(ws[OFF_BRGB + 1]), br2 = bf2f(ws[OFF_BRGB + 2]);
    float bs = bf2f(ws[OFF_BSIG]);
    int col = lane & 15;
#pragma unroll
    for (int r = 0; r < 4; ++r) {
      int row = wid * 16 + q * 4 + r;
      long p = (long)blk * 128 + row;
      float v = acc[r];
      if (col == 3) {
        float z = v + bs;
        float sp = (z > 20.0f) ? z : __logf(1.0f + __expf(z));
        stf(out, (long)3 * NPTS + p, isbf, sp);
      } else if (col < 3) {
        float z = v + (col == 0 ? br0 : (col == 1 ? br1 : br2));
        float sg = 1.0f / (1.0f + __expf(-z));
        stf(out, p * 3 + col, isbf, sg);
      }
    }
  }
}

extern "C" void kernel_launch(void* const* d_in, const int* in_sizes, int n_in,
                              void* d_out, int out_size, void* d_ws, size_t ws_size,
                              hipStream_t stream) {
  const void* x    = d_in[0];
  const void* fxy  = d_in[1];
  const void* fxz  = d_in[2];
  const void* fyz  = d_in[3];
  const void* W0   = d_in[4];
  const void* b0   = d_in[5];
  const void* W1   = d_in[6];
  const void* b1   = d_in[7];
  const void* W2   = d_in[8];
  const void* b2   = d_in[9];
  const void* W3   = d_in[10];
  const void* b3   = d_in[11];
  const void* Wsig = d_in[12];
  const void* bsig = d_in[13];
  const void* Wrgb = d_in[14];
  const void* brgb = d_in[15];
  ushort_t* ws = (ushort_t*)d_ws;

  hipLaunchKernelGGL(sniff_dtype, dim3(1), dim3(64), 0, stream, fxy, ws);
  hipLaunchKernelGGL(prep_bias, dim3(1), dim3(256), 0, stream,
                     b0, b1, b2, b3, bsig, brgb, ws);
  hipLaunchKernelGGL(prep_weights, dim3(106), dim3(256), 0, stream,
                     W0, W1, W2, W3, Wsig, Wrgb, ws);
  hipLaunchKernelGGL(prep_planes, dim3(192), dim3(256), 0, stream,
                     fxy, fxz, fyz, ws);
  hipLaunchKernelGGL(tensorf_main, dim3(8192), dim3(512), 0, stream,
                     x, ws, d_out);
}